// Round 9
// baseline (428.948 us; speedup 1.0000x reference)
//
#include <hip/hip_runtime.h>

typedef unsigned short u16;
typedef short  bfrag  __attribute__((ext_vector_type(8), may_alias)); // 8 bf16 (MFMA A/B)
typedef unsigned long long ull_a __attribute__((may_alias));
typedef int    int_a  __attribute__((may_alias));
typedef int    i4_a   __attribute__((ext_vector_type(4), may_alias));
typedef float  f4_a   __attribute__((ext_vector_type(4), may_alias));
typedef unsigned u32x2 __attribute__((ext_vector_type(2)));
typedef __attribute__((ext_vector_type(4)))  float facc4;   // 16x16 C/D
typedef __attribute__((ext_vector_type(16))) float facc16;  // 32x32 C/D

#define SEQ   2048
#define NHEAD 16
#define HD    64
#define DM    1024
#define BH    64        // B*NHEAD
#define NTOK  8192      // B*SEQ
// (1/sqrt(1024)) * log2(e), folded into Q at projection time
#define QSC   0.04508422f

#if defined(__has_builtin)
#if __has_builtin(__builtin_amdgcn_cvt_pk_bf16_f32)
#define HAS_CVT_PK 1
#endif
#if __has_builtin(__builtin_amdgcn_permlane32_swap)
#define HAS_PLSWAP 1
#endif
#endif
#ifndef HAS_CVT_PK
#define HAS_CVT_PK 0
#endif
#ifndef HAS_PLSWAP
#define HAS_PLSWAP 0
#endif

__device__ __forceinline__ u16 f2bf(float f){
  union { float f; unsigned u; } x; x.f = f;
  unsigned r = x.u + 0x7FFFu + ((x.u >> 16) & 1u);
  return (u16)(r >> 16);
}
__device__ __forceinline__ unsigned pk2(float a, float b){
#if HAS_CVT_PK
  auto r = __builtin_amdgcn_cvt_pk_bf16_f32(a, b);
  union { decltype(r) v; unsigned u; } x; x.v = r; return x.u;
#else
  return (unsigned)f2bf(a) | ((unsigned)f2bf(b) << 16);
#endif
}
__device__ __forceinline__ unsigned long long pk4(float a, float b, float c, float d){
  return (unsigned long long)pk2(a,b) | ((unsigned long long)pk2(c,d) << 32);
}
// cross-half (lane^32) word exchange: on return
//   a = [lanes<32: a(lo-half), lanes>=32: b(lo-half)]   (w0-role)
//   b = [lanes<32: a(hi-half), lanes>=32: b(hi-half)]   (w2-role)
__device__ __forceinline__ void swap32(unsigned &a, unsigned &b){
#if HAS_PLSWAP
  u32x2 r = __builtin_amdgcn_permlane32_swap(a, b, false, false);
  a = r[0]; b = r[1];
#else
  int lane = threadIdx.x & 63; int hh = lane >> 5;
  unsigned pa = (unsigned)__shfl_xor((int)a, 32, 64);
  unsigned pb = (unsigned)__shfl_xor((int)b, 32, 64);
  unsigned na = hh ? pb : a;
  unsigned nb = hh ? b  : pa;
  a = na; b = nb;
#endif
}
// load 8 consecutive f32 -> bf16 MFMA half-fragment
__device__ __forceinline__ bfrag ld8f(const float* p){
  f4_a a = *(const f4_a*)p;
  f4_a b = *(const f4_a*)(p + 4);
  union { bfrag v; unsigned u[4]; } r;
  r.u[0] = pk2(a[0],a[1]); r.u[1] = pk2(a[2],a[3]);
  r.u[2] = pk2(b[0],b[1]); r.u[3] = pk2(b[2],b[3]);
  return r.v;
}
// async global->LDS, 16B per lane; LDS dest = wave-uniform base + lane*16
__device__ __forceinline__ void stage16(const u16* g, u16* l){
  __builtin_amdgcn_global_load_lds((const __attribute__((address_space(1))) void*)g,
                                   (__attribute__((address_space(3))) void*)l, 16, 0, 0);
}
__device__ __forceinline__ void stage16f(const float* g, float* l){
  __builtin_amdgcn_global_load_lds((const __attribute__((address_space(1))) void*)g,
                                   (__attribute__((address_space(3))) void*)l, 16, 0, 0);
}

// ---------------------------------------------------------------------------
// Kernel 0: convert wo (1M, linear) + wq/wk/wv (4K each, MFMA-FRAGMENT order)
// f32 -> bf16.  (R6-verified, FROZEN.)
__global__ __launch_bounds__(256) void k_wconv(
  const float* __restrict__ wo, const float* __restrict__ wq,
  const float* __restrict__ wk, const float* __restrict__ wv,
  u16* __restrict__ dst)
{
  long i = ((long)blockIdx.x * 256 + threadIdx.x) * 8;
  if (i < 1048576){
    f4_a a = *(const f4_a*)(wo + i);
    f4_a b = *(const f4_a*)(wo + i + 4);
    ull_a* p = (ull_a*)(dst + i);
    p[0] = pk4(a[0],a[1],a[2],a[3]);
    p[1] = pk4(b[0],b[1],b[2],b[3]);
  } else {
    long o = i - 1048576;
    int m  = (int)(o >> 12);            // 0=q, 1=k, 2=v (4096 elems each)
    int oo = (int)(o & 4095);
    const float* src = (m == 0) ? wq : ((m == 1) ? wk : wv);
    int lane = (oo >> 3) & 63, ks = (oo >> 9) & 3, dt = (oo >> 11);
    int soff = (dt*32 + (lane & 31))*64 + ks*16 + (lane >> 5)*8;
    f4_a a = *(const f4_a*)(src + soff);
    f4_a b = *(const f4_a*)(src + soff + 4);
    ull_a* p = (ull_a*)(dst + i);
    p[0] = pk4(a[0],a[1],a[2],a[3]);
    p[1] = pk4(b[0],b[1],b[2],b[3]);
  }
}

// ---------------------------------------------------------------------------
// Kernel 1 (v3): QKV projection as transposed GEMM, DMA-staged x.
// (R6-verified, FROZEN.)
__global__ __launch_bounds__(256) void k_proj(
  const float* __restrict__ vin, const float* __restrict__ kin, const float* __restrict__ qin,
  const u16* __restrict__ wqb, const u16* __restrict__ wkb, const u16* __restrict__ wvb,
  const float* __restrict__ bq, const float* __restrict__ bk, const float* __restrict__ bv,
  u16* __restrict__ qo, u16* __restrict__ ko, u16* __restrict__ vt)
{
  __shared__ __align__(16) float Xs[2][64*64];          // 2 x 16 KB, swizzled
  __shared__ __align__(16) u16 LTq[64*68], LTk[64*68];  // 17.4 KB
  int tid = threadIdx.x;
  int wid = tid >> 6, lane = tid & 63;
  int ln = lane & 31, hh = lane >> 5;
  int tt = wid & 1, dt = wid >> 1;
  int h  = blockIdx.y;
  int t0 = blockIdx.x * 64;
  int b  = t0 >> 11, s0 = t0 & 2047;   // 64 | 2048 -> never straddles b
  int bh = b * NHEAD + h;

  // stage one matrix's 64x64 f32 tile: instr g covers rows g*4..g*4+3;
  // lane l -> row rl = g*4 + (l>>4), slot l&15, global chunk (l&15)^(rl&15)
  auto stage_mat = [&](const float* __restrict__ x, int buf){
    #pragma unroll
    for (int j = 0; j < 4; j++){
      int g  = wid*4 + j;
      int rl = g*4 + (lane >> 4);
      int cg = (lane & 15) ^ (rl & 15);
      stage16f(x + (long)(t0 + rl)*DM + h*HD + cg*4, &Xs[buf][g*4*64]);
    }
  };
  // B-fragment: lane's token row r = tt*32+ln; f32 chunks c0,c0+1 at XORed slots
  auto bfr = [&](int buf, int ks){
    int r  = tt*32 + ln;
    int c0 = ks*4 + hh*2;
    const f4_a* base = (const f4_a*)&Xs[buf][r*64];
    f4_a a = base[ c0      ^ (r & 15)];
    f4_a b = base[(c0 + 1) ^ (r & 15)];
    union { bfrag v; unsigned u[4]; } rr;
    rr.u[0] = pk2(a[0],a[1]); rr.u[1] = pk2(a[2],a[3]);
    rr.u[2] = pk2(b[0],b[1]); rr.u[3] = pk2(b[2],b[3]);
    return rr.v;
  };
  // one 32x32 tile: A = weight fragments (contiguous), B = staged x
  auto mm = [&](const u16* __restrict__ wb, int buf){
    facc16 a;
    #pragma unroll
    for (int r = 0; r < 16; r++) a[r] = 0.f;
    #pragma unroll
    for (int ks = 0; ks < 4; ks++){
      bfrag aw = *(const bfrag*)(wb + ((dt*4 + ks)*64 + lane)*8);
      a = __builtin_amdgcn_mfma_f32_32x32x16_bf16(aw, bfr(buf, ks), a, 0,0,0);
    }
    return a;
  };
  // C layout (32x32): col = lane&31 = tok, row d = g*8 + 4*hh + (r&3), g=r>>2.

  stage_mat(vin, 0);
  stage_mat(qin, 1);
  __syncthreads();                    // drains DMA -> V,Q tiles ready

  // ---- V: C[d][tok] == vt[bh][d][s] -> direct stores ----
  {
    facc16 acc = mm(wvb, 0);
    int s = s0 + tt*32 + ln;
    long vb = (long)bh * HD * SEQ + s;
    #pragma unroll
    for (int g = 0; g < 4; g++){
      f4_a bb = *(const f4_a*)(bv + dt*32 + g*8 + 4*hh);
      #pragma unroll
      for (int j = 0; j < 4; j++)
        vt[vb + (long)(dt*32 + g*8 + 4*hh + j) * SEQ] = f2bf(acc[g*4+j] + bb[j]);
    }
  }
  __syncthreads();                    // X0 free for K
  stage_mat(kin, 0);

  // ---- Q -> LTq (scaled) ----
  {
    facc16 acc = mm(wqb, 1);
    int row = tt*32 + ln;
    #pragma unroll
    for (int g = 0; g < 4; g++){
      f4_a bb = *(const f4_a*)(bq + dt*32 + g*8 + 4*hh);
      *(ull_a*)&LTq[row*68 + dt*32 + g*8 + 4*hh] =
        pk4((acc[g*4+0]+bb[0])*QSC, (acc[g*4+1]+bb[1])*QSC,
            (acc[g*4+2]+bb[2])*QSC, (acc[g*4+3]+bb[3])*QSC);
    }
  }
  __syncthreads();                    // K staged (drain) + LTq visible

  // store Q: thread t -> row rr = t/4, 16-elem quarter q4 = t&3
  {
    int rr = tid >> 2, q4 = tid & 3;
    long gb = ((long)bh * SEQ + s0 + rr) * HD + q4*16;
    *(i4_a*)(qo + gb)     = *(const i4_a*)&LTq[rr*68 + q4*16];
    *(i4_a*)(qo + gb + 8) = *(const i4_a*)&LTq[rr*68 + q4*16 + 8];
  }

  // ---- K -> LTk ----
  {
    facc16 acc = mm(wkb, 0);
    int row = tt*32 + ln;
    #pragma unroll
    for (int g = 0; g < 4; g++){
      f4_a bb = *(const f4_a*)(bk + dt*32 + g*8 + 4*hh);
      *(ull_a*)&LTk[row*68 + dt*32 + g*8 + 4*hh] =
        pk4(acc[g*4+0]+bb[0], acc[g*4+1]+bb[1],
            acc[g*4+2]+bb[2], acc[g*4+3]+bb[3]);
    }
  }
  __syncthreads();
  {
    int rr = tid >> 2, q4 = tid & 3;
    long gb = ((long)bh * SEQ + s0 + rr) * HD + q4*16;
    *(i4_a*)(ko + gb)     = *(const i4_a*)&LTk[rr*68 + q4*16];
    *(i4_a*)(ko + gb + 8) = *(const i4_a*)&LTk[rr*68 + q4*16 + 8];
  }
}

// ---------------------------------------------------------------------------
// Kernel 3: flash attention.  R8 trims REVERTED (VALUBusy fell but dur rose:
// not issue-count-bound -> limiter is barrier lockstep + dep latency).
// THIS ROUND'S ONE CHANGE: KVBLK 64 -> 128 -- stage TWO K-tiles + TWO
// V-tiles per barrier; barrier count halves (32 -> 16/block).  Staging
// instrs per key unchanged (4/wave per double-tile).  LDS 32 -> 64 KB,
// still 2 blocks/CU (grid-limited; 128 KB < 160 KB, so NO occupancy loss
// -- the m132 BK-doubling penalty doesn't apply here).  V tile is now
// 64d x 128s with a 16-slot XOR swizzle (slot c^(d&15): lanes ln, ln+16
// alias -> 2-way, free).  K keeps the proven 8-chunk swizzle.  Per-sub-tile
// compute body is R6-exact, run twice per barrier with compile-time sub.
// XCD pinning [R2: FETCH 24.6 MB], in-register P fragments (T12),
// no online max (scores bounded), Q pre-scaled: p=exp2(E).
__global__ __launch_bounds__(512, 4) void k_attn(
  const u16* __restrict__ qws, const u16* __restrict__ kws, const u16* __restrict__ vt,
  u16* __restrict__ aout)
{
  __shared__ __align__(16) u16 Kb[2][128*64];   // [buf][key][64e] swizzled, 32 KB
  __shared__ __align__(16) u16 Vb[2][64*128];   // [buf][d][128s] swizzled, 32 KB
  int tid = threadIdx.x;
  int wid = tid >> 6, lane = tid & 63;
  int ln = lane & 31, hh = lane >> 5;
  int bid = blockIdx.x;
  int xcd = bid & 7, lix = bid >> 3;        // lix 0..63
  int bh = xcd * 8 + (lix >> 3);            // 8 bh panels per XCD
  int q0 = (lix & 7) * 256 + wid * 32;
  long base = (long)bh * SEQ * HD;    // same element offset for qws/kws/vt

  // K staging: instr covers 8 rows (64 lanes x 16B). lane l -> row (l>>3),
  // slot l&7; global chunk fetched = (l&7) ^ (l>>3)  (8-chunk XOR).
  int srow   = lane >> 3;
  int schunk = (lane & 7) ^ srow;
  // V staging: instr covers 4 d-rows of 256B. lane l -> row (l>>4),
  // slot l&15; global s-chunk fetched = (l&15) ^ (row&15)  (16-slot XOR).
  int vrow = lane >> 4;

  bfrag qf[4];                        // B frag: Qᵀ[e][q], lane n=ln=q, k=e chunk
  #pragma unroll
  for (int ks = 0; ks < 4; ks++)
    qf[ks] = *(const bfrag*)(qws + base + (long)(q0 + ln)*HD + ks*16 + hh*8);

  facc16 OO0, OO1;
  #pragma unroll
  for (int r = 0; r < 16; r++){ OO0[r] = 0.f; OO1[r] = 0.f; }
  float l_ = 0.f;                     // own-half partial; partner-summed in epilogue

  // prologue: stage double-tile 0 into buf 0; wave w owns groups {w, w+8}
  #pragma unroll
  for (int g2 = 0; g2 < 2; g2++){
    int g = wid + g2*8;
    stage16(kws + base + (long)(g*8 + srow)*HD + schunk*8, &Kb[0][g*512]);
    int cgv = (lane & 15) ^ ((g*4 + vrow) & 15);
    stage16(vt  + base + (long)(g*4 + vrow)*SEQ + cgv*8,   &Vb[0][g*512]);
  }

  auto dtile = [&](int buf, int t){
    __syncthreads();                  // drains own DMA (vmcnt 0) -> buf ready
    if (t + 1 < 16){                  // prefetch next double-tile
      int k0n = (t + 1) * 128;
      #pragma unroll
      for (int g2 = 0; g2 < 2; g2++){
        int g = wid + g2*8;
        stage16(kws + base + (long)(k0n + g*8 + srow)*HD + schunk*8, &Kb[buf^1][g*512]);
        int cgv = (lane & 15) ^ ((g*4 + vrow) & 15);
        stage16(vt  + base + (long)(g*4 + vrow)*SEQ + k0n + cgv*8,   &Vb[buf^1][g*512]);
      }
    }

    #pragma unroll
    for (int sub = 0; sub < 2; sub++){
      // Eᵀ[key][q]: A = K[key][e] from LDS (swizzled), B = Qᵀ from registers
      facc16 E0, E1;
      #pragma unroll
      for (int r = 0; r < 16; r++){ E0[r] = 0.f; E1[r] = 0.f; }
      __builtin_amdgcn_s_setprio(1);
      #pragma unroll
      for (int ks = 0; ks < 4; ks++){
        int sw = ((2*ks + hh) ^ (ln & 7)) * 8;
        bfrag kf0 = *(const bfrag*)&Kb[buf][(sub*64 +      ln)*64 + sw];
        bfrag kf1 = *(const bfrag*)&Kb[buf][(sub*64 + 32 + ln)*64 + sw];
        E0 = __builtin_amdgcn_mfma_f32_32x32x16_bf16(kf0, qf[ks], E0, 0,0,0);
        E1 = __builtin_amdgcn_mfma_f32_32x32x16_bf16(kf1, qf[ks], E1, 0,0,0);
      }
      __builtin_amdgcn_s_setprio(0);

      // p = exp2(E); accumulate own-half l. Lane ln owns q-row ln entirely.
      float rs = 0.f;
      #pragma unroll
      for (int r = 0; r < 16; r++){
        float p0 = __builtin_amdgcn_exp2f(E0[r]);
        float p1 = __builtin_amdgcn_exp2f(E1[r]);
        E0[r] = p0; E1[r] = p1; rs += p0 + p1;
      }
      l_ += rs;

      // P -> bf16 B-fragments in-register: pf[ks] holds keys ks*16+hh*8+{0..7}
      // (within this 64-key sub-tile) for q=ln.  C-layout: E[r] = key
      // (r&3)+8*(r>>2)+4*hh.  One swap32 of (local-pair, +4-pair) yields both
      // the w0 word (own half) and the w2 word (partner half).
      bfrag pf[4];
      #pragma unroll
      for (int half = 0; half < 2; half++){
        const facc16& P = half ? E1 : E0;
        #pragma unroll
        for (int k2 = 0; k2 < 2; k2++){
          int rb = k2 * 8;
          unsigned A0 = pk2(P[rb+0], P[rb+1]);
          unsigned A1 = pk2(P[rb+2], P[rb+3]);
          unsigned B0 = pk2(P[rb+4], P[rb+5]);
          unsigned B1 = pk2(P[rb+6], P[rb+7]);
          swap32(A0, B0);               // A0 -> w0, B0 -> w2
          swap32(A1, B1);               // A1 -> w1, B1 -> w3
          union { bfrag v; unsigned u[4]; } tt;
          tt.u[0] = A0; tt.u[1] = A1; tt.u[2] = B0; tt.u[3] = B1;
          pf[half*2 + k2] = tt.v;
        }
      }

      // Oᵀ[dv][q] += Vᵀ·Pᵀ  (V row = d, 128-u16 stride, 16-slot swizzle;
      // absolute key chunk = sub*8 + 2*ks + hh)
      __builtin_amdgcn_s_setprio(1);
      #pragma unroll
      for (int ks = 0; ks < 4; ks++){
        int swv = ((sub*8 + 2*ks + hh) ^ (ln & 15)) * 8;
        bfrag vf0 = *(const bfrag*)&Vb[buf][ ln      *128 + swv];
        bfrag vf1 = *(const bfrag*)&Vb[buf][(32 + ln)*128 + swv];
        OO0 = __builtin_amdgcn_mfma_f32_32x32x16_bf16(vf0, pf[ks], OO0, 0,0,0);
        OO1 = __builtin_amdgcn_mfma_f32_32x32x16_bf16(vf1, pf[ks], OO1, 0,0,0);
      }
      __builtin_amdgcn_s_setprio(0);
    }
  };

  for (int t = 0; t < 16; t += 2){
    dtile(0, t);
    dtile(1, t + 1);
  }

  // epilogue: O[q][dv] = OOᵀ / l; store [B,S,H,D] bf16
  l_ += __shfl_xor(l_, 32, 64);       // partner holds the other 32 keys/tile
  float inv = 1.0f / l_;
  int b_ = bh >> 4, h_ = bh & 15;
  long orow = ((long)(b_ * SEQ + q0 + ln) * NHEAD + h_) * HD;
  #pragma unroll
  for (int g = 0; g < 4; g++){
    *(ull_a*)(aout + orow +      8*g + 4*hh) =
      pk4(OO0[4*g]*inv, OO0[4*g+1]*inv, OO0[4*g+2]*inv, OO0[4*g+3]*inv);
    *(ull_a*)(aout + orow + 32 + 8*g + 4*hh) =
      pk4(OO1[4*g]*inv, OO1[4*g+1]*inv, OO1[4*g+2]*inv, OO1[4*g+3]*inv);
  }
}

// ---------------------------------------------------------------------------
// Kernel 4: output projection out = A @ wo.T + bo.
// (R5-verified version, byte-for-byte. FROZEN.)
__global__ __launch_bounds__(256, 2) void k_oproj(
  const u16* __restrict__ A, const u16* __restrict__ Bw,
  const float* __restrict__ bo, float* __restrict__ out)
{
  __shared__ __align__(16) u16 As[2][128*64];   // 2 x 16 KB
  __shared__ __align__(16) u16 Bs[2][128*64];   // 2 x 16 KB
  int tid  = threadIdx.x;
  int wid  = tid >> 6, lane = tid & 63;
  int quad = lane >> 4, col = lane & 15;
  int bid = blockIdx.x;
  int xcd = bid & 7, lix = bid >> 3;        // 64 blocks per XCD
  int m0 = (xcd * 8 + (lix >> 3)) * 128;    // 8 m-tiles per XCD
  int n0 = (lix & 7) * 128;                 // all 8 n-tiles
  int wm = (wid & 1) * 64, wn = (wid >> 1) * 64;

  facc4 acc[4][4];
  #pragma unroll
  for (int i = 0; i < 4; i++)
    #pragma unroll
    for (int j = 0; j < 4; j++) acc[i][j] = {0.f,0.f,0.f,0.f};

  int srow   = lane >> 3;                   // staging row within 8-row group
  int schunk = (lane & 7) ^ srow;           // XOR-swizzled global chunk
  const u16* Ag = A  + (long)(m0 + wid*8 + srow) * DM + schunk*8;
  const u16* Bg = Bw + (long)(n0 + wid*8 + srow) * DM + schunk*8;

  // prologue: stage k-tile 0 into buf 0
  #pragma unroll
  for (int j = 0; j < 4; j++){
    stage16(Ag + (long)j*32*DM, &As[0][(j*32 + wid*8)*64]);
    stage16(Bg + (long)j*32*DM, &Bs[0][(j*32 + wid*8)*64]);
  }

  auto kstep = [&](int buf, int kt){
    __syncthreads();                        // drains own DMA -> buf ready
    if (kt + 1 < 16){
      long k0 = (long)(kt + 1) * 64;
      #pragma unroll
      for (int j = 0; j < 4; j++){
        stage16(Ag + (long)j*32*DM + k0, &As[buf^1][(j*32 + wid*8)*64]);
        stage16(Bg + (long)j*32*DM + k0, &Bs[buf^1][(j*32 + wid*8)*64]);
      }
    }
    #pragma unroll
    for (int ks = 0; ks < 2; ks++){
      bfrag af[4], bf[4];
      #pragma unroll
      for (int i = 0; i < 4; i++){
        int row = wm + i*16 + col;
        af[i] = *(const bfrag*)&As[buf][row*64 + ((ks*4 + quad) ^ (col & 7))*8];
      }
      #pragma unroll
      for (int i = 0; i < 4; i++){
        int row = wn + i*16 + col;
        bf[i] = *(const bfrag*)&Bs[buf][row*64 + ((ks*4 + quad) ^ (col & 7))*8];
      }
      #pragma unroll
      for (int i = 0; i < 4; i++)
        #pragma unroll
        for (int j = 0; j < 4; j++)
          acc[i][j] = __builtin_amdgcn_mfma_f32_16x16x32_bf16(af[i], bf[j], acc[i][j], 0,0,0);
    }
  };

  for (int kt = 0; kt < 16; kt += 2){
    kstep(0, kt);
    kstep(1, kt + 1);
  }

  #pragma unroll
  for (int j = 0; j < 4; j++){
    int n = n0 + wn + j*16 + col;
    float bias = bo[n];
    #pragma unroll
    for (int i = 0; i < 4; i++){
      long mrow = m0 + wm + i*16 + quad*4;
      #pragma unroll
      for (int r = 0; r < 4; r++)
        out[(mrow + r) * DM + n] = acc[i][j][r] + bias;
    }
  }
}

// ---------------------------------------------------------------------------
extern "C" void kernel_launch(void* const* d_in, const int* in_sizes, int n_in,
                              void* d_out, int out_size, void* d_ws, size_t ws_size,
                              hipStream_t stream)
{
  const float* values = (const float*)d_in[0];
  const float* keys   = (const float*)d_in[1];
  const float* query  = (const float*)d_in[2];
  const float* wq = (const float*)d_in[3];
  const float* bq = (const float*)d_in[4];
  const float* wk = (const float*)d_in[5];
  const float* bk = (const float*)d_in[6];
  const float* wv = (const float*)d_in[7];
  const float* bv = (const float*)d_in[8];
  const float* wo = (const float*)d_in[9];
  const float* bo = (const float*)d_in[10];

  const long N = 8388608;             // B*H*S*D elements
  u16* qws  = (u16*)d_ws;             // bf16 intermediates
  u16* kws  = qws  + N;
  u16* vws  = kws  + N;               // attn output scratch
  u16* vtws = vws  + N;               // V, produced transposed by k_proj
  u16* wob  = vtws + N;               // 1M elems (wo bf16, linear)
  u16* wqb  = wob + 1048576;          // 4K elems each, FRAGMENT layout
  u16* wkb  = wqb + 4096;
  u16* wvb  = wkb + 4096;
  u16* aws  = vws;

  k_wconv <<<518,           256, 0, stream>>>(wo, wq, wk, wv, wob);
  k_proj  <<<dim3(128, 16), 256, 0, stream>>>(values, keys, query, wqb, wkb, wvb,
                                              bq, bk, bv, qws, kws, vtws);
  k_attn  <<<512,           512, 0, stream>>>(qws, kws, vtws, aws);
  k_oproj <<<512,           256, 0, stream>>>(aws, wob, bo, (float*)d_out);
}

// Round 10
// 269.275 us; speedup vs baseline: 1.5930x; 1.5930x over previous
//
#include <hip/hip_runtime.h>

typedef unsigned short u16;
typedef short  bfrag  __attribute__((ext_vector_type(8), may_alias)); // 8 bf16 (MFMA A/B)
typedef unsigned long long ull_a __attribute__((may_alias));
typedef int    int_a  __attribute__((may_alias));
typedef int    i4_a   __attribute__((ext_vector_type(4), may_alias));
typedef float  f4_a   __attribute__((ext_vector_type(4), may_alias));
typedef unsigned u32x2 __attribute__((ext_vector_type(2)));
typedef __attribute__((ext_vector_type(4)))  float facc4;   // 16x16 C/D
typedef __attribute__((ext_vector_type(16))) float facc16;  // 32x32 C/D

#define SEQ   2048
#define NHEAD 16
#define HD    64
#define DM    1024
#define BH    64        // B*NHEAD
#define NTOK  8192      // B*SEQ
// (1/sqrt(1024)) * log2(e), folded into Q at projection time
#define QSC   0.04508422f

#if defined(__has_builtin)
#if __has_builtin(__builtin_amdgcn_cvt_pk_bf16_f32)
#define HAS_CVT_PK 1
#endif
#if __has_builtin(__builtin_amdgcn_permlane32_swap)
#define HAS_PLSWAP 1
#endif
#endif
#ifndef HAS_CVT_PK
#define HAS_CVT_PK 0
#endif
#ifndef HAS_PLSWAP
#define HAS_PLSWAP 0
#endif

__device__ __forceinline__ u16 f2bf(float f){
  union { float f; unsigned u; } x; x.f = f;
  unsigned r = x.u + 0x7FFFu + ((x.u >> 16) & 1u);
  return (u16)(r >> 16);
}
__device__ __forceinline__ unsigned pk2(float a, float b){
#if HAS_CVT_PK
  auto r = __builtin_amdgcn_cvt_pk_bf16_f32(a, b);
  union { decltype(r) v; unsigned u; } x; x.v = r; return x.u;
#else
  return (unsigned)f2bf(a) | ((unsigned)f2bf(b) << 16);
#endif
}
__device__ __forceinline__ unsigned long long pk4(float a, float b, float c, float d){
  return (unsigned long long)pk2(a,b) | ((unsigned long long)pk2(c,d) << 32);
}
// cross-half (lane^32) word exchange: on return
//   a = [lanes<32: a(lo-half), lanes>=32: b(lo-half)]   (w0-role)
//   b = [lanes<32: a(hi-half), lanes>=32: b(hi-half)]   (w2-role)
__device__ __forceinline__ void swap32(unsigned &a, unsigned &b){
#if HAS_PLSWAP
  u32x2 r = __builtin_amdgcn_permlane32_swap(a, b, false, false);
  a = r[0]; b = r[1];
#else
  int lane = threadIdx.x & 63; int hh = lane >> 5;
  unsigned pa = (unsigned)__shfl_xor((int)a, 32, 64);
  unsigned pb = (unsigned)__shfl_xor((int)b, 32, 64);
  unsigned na = hh ? pb : a;
  unsigned nb = hh ? b  : pa;
  a = na; b = nb;
#endif
}
// load 8 consecutive f32 -> bf16 MFMA half-fragment
__device__ __forceinline__ bfrag ld8f(const float* p){
  f4_a a = *(const f4_a*)p;
  f4_a b = *(const f4_a*)(p + 4);
  union { bfrag v; unsigned u[4]; } r;
  r.u[0] = pk2(a[0],a[1]); r.u[1] = pk2(a[2],a[3]);
  r.u[2] = pk2(b[0],b[1]); r.u[3] = pk2(b[2],b[3]);
  return r.v;
}
// async global->LDS, 16B per lane; LDS dest = wave-uniform base + lane*16
__device__ __forceinline__ void stage16(const u16* g, u16* l){
  __builtin_amdgcn_global_load_lds((const __attribute__((address_space(1))) void*)g,
                                   (__attribute__((address_space(3))) void*)l, 16, 0, 0);
}
__device__ __forceinline__ void stage16f(const float* g, float* l){
  __builtin_amdgcn_global_load_lds((const __attribute__((address_space(1))) void*)g,
                                   (__attribute__((address_space(3))) void*)l, 16, 0, 0);
}

// ---------------------------------------------------------------------------
// Kernel 0: convert wo (1M, linear) + wq/wk/wv (4K each, MFMA-FRAGMENT order)
// f32 -> bf16.  (R6-verified, FROZEN.)
__global__ __launch_bounds__(256) void k_wconv(
  const float* __restrict__ wo, const float* __restrict__ wq,
  const float* __restrict__ wk, const float* __restrict__ wv,
  u16* __restrict__ dst)
{
  long i = ((long)blockIdx.x * 256 + threadIdx.x) * 8;
  if (i < 1048576){
    f4_a a = *(const f4_a*)(wo + i);
    f4_a b = *(const f4_a*)(wo + i + 4);
    ull_a* p = (ull_a*)(dst + i);
    p[0] = pk4(a[0],a[1],a[2],a[3]);
    p[1] = pk4(b[0],b[1],b[2],b[3]);
  } else {
    long o = i - 1048576;
    int m  = (int)(o >> 12);            // 0=q, 1=k, 2=v (4096 elems each)
    int oo = (int)(o & 4095);
    const float* src = (m == 0) ? wq : ((m == 1) ? wk : wv);
    int lane = (oo >> 3) & 63, ks = (oo >> 9) & 3, dt = (oo >> 11);
    int soff = (dt*32 + (lane & 31))*64 + ks*16 + (lane >> 5)*8;
    f4_a a = *(const f4_a*)(src + soff);
    f4_a b = *(const f4_a*)(src + soff + 4);
    ull_a* p = (ull_a*)(dst + i);
    p[0] = pk4(a[0],a[1],a[2],a[3]);
    p[1] = pk4(b[0],b[1],b[2],b[3]);
  }
}

// ---------------------------------------------------------------------------
// Kernel 1 (v3): QKV projection as transposed GEMM, DMA-staged x.
// (R6-verified, FROZEN.)
__global__ __launch_bounds__(256) void k_proj(
  const float* __restrict__ vin, const float* __restrict__ kin, const float* __restrict__ qin,
  const u16* __restrict__ wqb, const u16* __restrict__ wkb, const u16* __restrict__ wvb,
  const float* __restrict__ bq, const float* __restrict__ bk, const float* __restrict__ bv,
  u16* __restrict__ qo, u16* __restrict__ ko, u16* __restrict__ vt)
{
  __shared__ __align__(16) float Xs[2][64*64];          // 2 x 16 KB, swizzled
  __shared__ __align__(16) u16 LTq[64*68], LTk[64*68];  // 17.4 KB
  int tid = threadIdx.x;
  int wid = tid >> 6, lane = tid & 63;
  int ln = lane & 31, hh = lane >> 5;
  int tt = wid & 1, dt = wid >> 1;
  int h  = blockIdx.y;
  int t0 = blockIdx.x * 64;
  int b  = t0 >> 11, s0 = t0 & 2047;   // 64 | 2048 -> never straddles b
  int bh = b * NHEAD + h;

  // stage one matrix's 64x64 f32 tile: instr g covers rows g*4..g*4+3;
  // lane l -> row rl = g*4 + (l>>4), slot l&15, global chunk (l&15)^(rl&15)
  auto stage_mat = [&](const float* __restrict__ x, int buf){
    #pragma unroll
    for (int j = 0; j < 4; j++){
      int g  = wid*4 + j;
      int rl = g*4 + (lane >> 4);
      int cg = (lane & 15) ^ (rl & 15);
      stage16f(x + (long)(t0 + rl)*DM + h*HD + cg*4, &Xs[buf][g*4*64]);
    }
  };
  // B-fragment: lane's token row r = tt*32+ln; f32 chunks c0,c0+1 at XORed slots
  auto bfr = [&](int buf, int ks){
    int r  = tt*32 + ln;
    int c0 = ks*4 + hh*2;
    const f4_a* base = (const f4_a*)&Xs[buf][r*64];
    f4_a a = base[ c0      ^ (r & 15)];
    f4_a b = base[(c0 + 1) ^ (r & 15)];
    union { bfrag v; unsigned u[4]; } rr;
    rr.u[0] = pk2(a[0],a[1]); rr.u[1] = pk2(a[2],a[3]);
    rr.u[2] = pk2(b[0],b[1]); rr.u[3] = pk2(b[2],b[3]);
    return rr.v;
  };
  // one 32x32 tile: A = weight fragments (contiguous), B = staged x
  auto mm = [&](const u16* __restrict__ wb, int buf){
    facc16 a;
    #pragma unroll
    for (int r = 0; r < 16; r++) a[r] = 0.f;
    #pragma unroll
    for (int ks = 0; ks < 4; ks++){
      bfrag aw = *(const bfrag*)(wb + ((dt*4 + ks)*64 + lane)*8);
      a = __builtin_amdgcn_mfma_f32_32x32x16_bf16(aw, bfr(buf, ks), a, 0,0,0);
    }
    return a;
  };
  // C layout (32x32): col = lane&31 = tok, row d = g*8 + 4*hh + (r&3), g=r>>2.

  stage_mat(vin, 0);
  stage_mat(qin, 1);
  __syncthreads();                    // drains DMA -> V,Q tiles ready

  // ---- V: C[d][tok] == vt[bh][d][s] -> direct stores ----
  {
    facc16 acc = mm(wvb, 0);
    int s = s0 + tt*32 + ln;
    long vb = (long)bh * HD * SEQ + s;
    #pragma unroll
    for (int g = 0; g < 4; g++){
      f4_a bb = *(const f4_a*)(bv + dt*32 + g*8 + 4*hh);
      #pragma unroll
      for (int j = 0; j < 4; j++)
        vt[vb + (long)(dt*32 + g*8 + 4*hh + j) * SEQ] = f2bf(acc[g*4+j] + bb[j]);
    }
  }
  __syncthreads();                    // X0 free for K
  stage_mat(kin, 0);

  // ---- Q -> LTq (scaled) ----
  {
    facc16 acc = mm(wqb, 1);
    int row = tt*32 + ln;
    #pragma unroll
    for (int g = 0; g < 4; g++){
      f4_a bb = *(const f4_a*)(bq + dt*32 + g*8 + 4*hh);
      *(ull_a*)&LTq[row*68 + dt*32 + g*8 + 4*hh] =
        pk4((acc[g*4+0]+bb[0])*QSC, (acc[g*4+1]+bb[1])*QSC,
            (acc[g*4+2]+bb[2])*QSC, (acc[g*4+3]+bb[3])*QSC);
    }
  }
  __syncthreads();                    // K staged (drain) + LTq visible

  // store Q: thread t -> row rr = t/4, 16-elem quarter q4 = t&3
  {
    int rr = tid >> 2, q4 = tid & 3;
    long gb = ((long)bh * SEQ + s0 + rr) * HD + q4*16;
    *(i4_a*)(qo + gb)     = *(const i4_a*)&LTq[rr*68 + q4*16];
    *(i4_a*)(qo + gb + 8) = *(const i4_a*)&LTq[rr*68 + q4*16 + 8];
  }

  // ---- K -> LTk ----
  {
    facc16 acc = mm(wkb, 0);
    int row = tt*32 + ln;
    #pragma unroll
    for (int g = 0; g < 4; g++){
      f4_a bb = *(const f4_a*)(bk + dt*32 + g*8 + 4*hh);
      *(ull_a*)&LTk[row*68 + dt*32 + g*8 + 4*hh] =
        pk4(acc[g*4+0]+bb[0], acc[g*4+1]+bb[1],
            acc[g*4+2]+bb[2], acc[g*4+3]+bb[3]);
    }
  }
  __syncthreads();
  {
    int rr = tid >> 2, q4 = tid & 3;
    long gb = ((long)bh * SEQ + s0 + rr) * HD + q4*16;
    *(i4_a*)(ko + gb)     = *(const i4_a*)&LTk[rr*68 + q4*16];
    *(i4_a*)(ko + gb + 8) = *(const i4_a*)&LTk[rr*68 + q4*16 + 8];
  }
}

// ---------------------------------------------------------------------------
// Kernel 3: flash attention, transposed formulation, MFMA 32x32x16.
// RESTORED to the R6-measured best (94.4 us): 8-wave/256-q blocks, grid 512,
// KVBLK=64, no VALU trims.  Post-R9 lesson: KVBLK=128 under
// __launch_bounds__(512,4)'s 128-VGPR cap spills accumulators to scratch
// (FETCH/WRITE ~470/489 MB symmetric) -- 2.6x regression.  R7 showed 4-wave
// blocks lose staging amortization; R8 showed VALU-count trims don't help
// (latency/barrier-bound, not issue-bound).  This structure is the verified
// local optimum of the per-tile-barrier design.
// XCD pinning [R2: FETCH 139->24.6 MB], double-buffered global_load_lds with
// compile-time buf, in-register P fragments (T12: cvt_pk + permlane32_swap),
// no online max (scores bounded), Q pre-scaled: p=exp2(E).
__global__ __launch_bounds__(512, 4) void k_attn(
  const u16* __restrict__ qws, const u16* __restrict__ kws, const u16* __restrict__ vt,
  u16* __restrict__ aout)
{
  __shared__ __align__(16) u16 KV[2][2][64*64];  // [buf][K/V][row][64] swizzled, 32 KB
  int tid = threadIdx.x;
  int wid = tid >> 6, lane = tid & 63;
  int ln = lane & 31, hh = lane >> 5;
  int bid = blockIdx.x;
  int xcd = bid & 7, lix = bid >> 3;        // lix 0..63
  int bh = xcd * 8 + (lix >> 3);            // 8 bh panels per XCD
  int q0 = (lix & 7) * 256 + wid * 32;
  long base = (long)bh * SEQ * HD;    // same element offset for qws/kws/vt

  // staging map: one instr covers 8 rows (64 lanes x 16B). lane l -> row (l>>3),
  // slot l&7; global chunk fetched = (l&7) ^ (l>>3)  (XOR swizzle).
  int srow   = lane >> 3;
  int schunk = (lane & 7) ^ srow;

  bfrag qf[4];                        // B frag: Qᵀ[e][q], lane n=ln=q, k=e chunk
  #pragma unroll
  for (int ks = 0; ks < 4; ks++)
    qf[ks] = *(const bfrag*)(qws + base + (long)(q0 + ln)*HD + ks*16 + hh*8);

  facc16 OO0, OO1;
  #pragma unroll
  for (int r = 0; r < 16; r++){ OO0[r] = 0.f; OO1[r] = 0.f; }
  float l_ = 0.f;                     // own-half partial; partner-summed in epilogue

  // prologue: stage tile 0 into buf 0 (async); wave w owns group w
  stage16(kws + base + (long)(wid*8 + srow)*HD + schunk*8,  &KV[0][0][wid*512]);
  stage16(vt  + base + (long)(wid*8 + srow)*SEQ + schunk*8, &KV[0][1][wid*512]);

  auto tile = [&](int buf, int kt){
    __syncthreads();                  // compiler drains own vmcnt(0) -> buf ready
    if (kt + 1 < 32){                 // prefetch next tile into other buffer
      int k0n = (kt + 1) * 64;
      stage16(kws + base + (long)(k0n + wid*8 + srow)*HD + schunk*8, &KV[buf^1][0][wid*512]);
      stage16(vt  + base + (long)(wid*8 + srow)*SEQ + k0n + schunk*8, &KV[buf^1][1][wid*512]);
    }

    // Eᵀ[key][q]: A = K[key][e] from LDS (swizzled), B = Qᵀ from registers
    facc16 E0, E1;
    #pragma unroll
    for (int r = 0; r < 16; r++){ E0[r] = 0.f; E1[r] = 0.f; }
    __builtin_amdgcn_s_setprio(1);
    #pragma unroll
    for (int ks = 0; ks < 4; ks++){
      int sw = ((2*ks + hh) ^ (ln & 7)) * 8;
      bfrag kf0 = *(const bfrag*)&KV[buf][0][ ln      *64 + sw];
      bfrag kf1 = *(const bfrag*)&KV[buf][0][(32 + ln)*64 + sw];
      E0 = __builtin_amdgcn_mfma_f32_32x32x16_bf16(kf0, qf[ks], E0, 0,0,0);
      E1 = __builtin_amdgcn_mfma_f32_32x32x16_bf16(kf1, qf[ks], E1, 0,0,0);
    }
    __builtin_amdgcn_s_setprio(0);

    // p = exp2(E); accumulate own-half l. Lane ln owns q-row ln entirely.
    float rs = 0.f;
    #pragma unroll
    for (int r = 0; r < 16; r++){
      float p0 = __builtin_amdgcn_exp2f(E0[r]);
      float p1 = __builtin_amdgcn_exp2f(E1[r]);
      E0[r] = p0; E1[r] = p1; rs += p0 + p1;
    }
    l_ += rs;

    // P -> bf16 B-fragments in-register: pf[ks] holds keys ks*16+hh*8+{0..7}
    // for q=ln.  C-layout: E[r] = key (r&3)+8*(r>>2)+4*hh.  One swap32 of
    // (local-pair, +4-pair) yields both the w0 word (own half) and the w2
    // word (partner half) of the fragment.
    bfrag pf[4];
    #pragma unroll
    for (int half = 0; half < 2; half++){
      const facc16& P = half ? E1 : E0;
      #pragma unroll
      for (int k2 = 0; k2 < 2; k2++){
        int rb = k2 * 8;
        unsigned A0 = pk2(P[rb+0], P[rb+1]);
        unsigned A1 = pk2(P[rb+2], P[rb+3]);
        unsigned B0 = pk2(P[rb+4], P[rb+5]);
        unsigned B1 = pk2(P[rb+6], P[rb+7]);
        swap32(A0, B0);               // A0 -> w0, B0 -> w2
        swap32(A1, B1);               // A1 -> w1, B1 -> w3
        union { bfrag v; unsigned u[4]; } t;
        t.u[0] = A0; t.u[1] = A1; t.u[2] = B0; t.u[3] = B1;
        pf[half*2 + k2] = t.v;
      }
    }

    // Oᵀ[dv][q] += Vᵀ·Pᵀ
    __builtin_amdgcn_s_setprio(1);
    #pragma unroll
    for (int ks = 0; ks < 4; ks++){
      int sw = ((2*ks + hh) ^ (ln & 7)) * 8;
      bfrag vf0 = *(const bfrag*)&KV[buf][1][ ln      *64 + sw];
      bfrag vf1 = *(const bfrag*)&KV[buf][1][(32 + ln)*64 + sw];
      OO0 = __builtin_amdgcn_mfma_f32_32x32x16_bf16(vf0, pf[ks], OO0, 0,0,0);
      OO1 = __builtin_amdgcn_mfma_f32_32x32x16_bf16(vf1, pf[ks], OO1, 0,0,0);
    }
    __builtin_amdgcn_s_setprio(0);
  };

  for (int kt = 0; kt < 32; kt += 2){
    tile(0, kt);
    tile(1, kt + 1);
  }

  // epilogue: O[q][dv] = OOᵀ / l; store [B,S,H,D] bf16
  l_ += __shfl_xor(l_, 32, 64);       // partner holds the other 32 keys/tile
  float inv = 1.0f / l_;
  int b_ = bh >> 4, h_ = bh & 15;
  long orow = ((long)(b_ * SEQ + q0 + ln) * NHEAD + h_) * HD;
  #pragma unroll
  for (int g = 0; g < 4; g++){
    *(ull_a*)(aout + orow +      8*g + 4*hh) =
      pk4(OO0[4*g]*inv, OO0[4*g+1]*inv, OO0[4*g+2]*inv, OO0[4*g+3]*inv);
    *(ull_a*)(aout + orow + 32 + 8*g + 4*hh) =
      pk4(OO1[4*g]*inv, OO1[4*g+1]*inv, OO1[4*g+2]*inv, OO1[4*g+3]*inv);
  }
}

// ---------------------------------------------------------------------------
// Kernel 4: output projection out = A @ wo.T + bo.
// (R5-verified version, byte-for-byte. FROZEN.)
__global__ __launch_bounds__(256, 2) void k_oproj(
  const u16* __restrict__ A, const u16* __restrict__ Bw,
  const float* __restrict__ bo, float* __restrict__ out)
{
  __shared__ __align__(16) u16 As[2][128*64];   // 2 x 16 KB
  __shared__ __align__(16) u16 Bs[2][128*64];   // 2 x 16 KB
  int tid  = threadIdx.x;
  int wid  = tid >> 6, lane = tid & 63;
  int quad = lane >> 4, col = lane & 15;
  int bid = blockIdx.x;
  int xcd = bid & 7, lix = bid >> 3;        // 64 blocks per XCD
  int m0 = (xcd * 8 + (lix >> 3)) * 128;    // 8 m-tiles per XCD
  int n0 = (lix & 7) * 128;                 // all 8 n-tiles
  int wm = (wid & 1) * 64, wn = (wid >> 1) * 64;

  facc4 acc[4][4];
  #pragma unroll
  for (int i = 0; i < 4; i++)
    #pragma unroll
    for (int j = 0; j < 4; j++) acc[i][j] = {0.f,0.f,0.f,0.f};

  int srow   = lane >> 3;                   // staging row within 8-row group
  int schunk = (lane & 7) ^ srow;           // XOR-swizzled global chunk
  const u16* Ag = A  + (long)(m0 + wid*8 + srow) * DM + schunk*8;
  const u16* Bg = Bw + (long)(n0 + wid*8 + srow) * DM + schunk*8;

  // prologue: stage k-tile 0 into buf 0
  #pragma unroll
  for (int j = 0; j < 4; j++){
    stage16(Ag + (long)j*32*DM, &As[0][(j*32 + wid*8)*64]);
    stage16(Bg + (long)j*32*DM, &Bs[0][(j*32 + wid*8)*64]);
  }

  auto kstep = [&](int buf, int kt){
    __syncthreads();                        // drains own DMA -> buf ready
    if (kt + 1 < 16){
      long k0 = (long)(kt + 1) * 64;
      #pragma unroll
      for (int j = 0; j < 4; j++){
        stage16(Ag + (long)j*32*DM + k0, &As[buf^1][(j*32 + wid*8)*64]);
        stage16(Bg + (long)j*32*DM + k0, &Bs[buf^1][(j*32 + wid*8)*64]);
      }
    }
    #pragma unroll
    for (int ks = 0; ks < 2; ks++){
      bfrag af[4], bf[4];
      #pragma unroll
      for (int i = 0; i < 4; i++){
        int row = wm + i*16 + col;
        af[i] = *(const bfrag*)&As[buf][row*64 + ((ks*4 + quad) ^ (col & 7))*8];
      }
      #pragma unroll
      for (int i = 0; i < 4; i++){
        int row = wn + i*16 + col;
        bf[i] = *(const bfrag*)&Bs[buf][row*64 + ((ks*4 + quad) ^ (col & 7))*8];
      }
      #pragma unroll
      for (int i = 0; i < 4; i++)
        #pragma unroll
        for (int j = 0; j < 4; j++)
          acc[i][j] = __builtin_amdgcn_mfma_f32_16x16x32_bf16(af[i], bf[j], acc[i][j], 0,0,0);
    }
  };

  for (int kt = 0; kt < 16; kt += 2){
    kstep(0, kt);
    kstep(1, kt + 1);
  }

  #pragma unroll
  for (int j = 0; j < 4; j++){
    int n = n0 + wn + j*16 + col;
    float bias = bo[n];
    #pragma unroll
    for (int i = 0; i < 4; i++){
      long mrow = m0 + wm + i*16 + quad*4;
      #pragma unroll
      for (int r = 0; r < 4; r++)
        out[(mrow + r) * DM + n] = acc[i][j][r] + bias;
    }
  }
}

// ---------------------------------------------------------------------------
extern "C" void kernel_launch(void* const* d_in, const int* in_sizes, int n_in,
                              void* d_out, int out_size, void* d_ws, size_t ws_size,
                              hipStream_t stream)
{
  const float* values = (const float*)d_in[0];
  const float* keys   = (const float*)d_in[1];
  const float* query  = (const float*)d_in[2];
  const float* wq = (const float*)d_in[3];
  const float* bq = (const float*)d_in[4];
  const float* wk = (const float*)d_in[5];
  const float* bk = (const float*)d_in[6];
  const float* wv = (const float*)d_in[7];
  const float* bv = (const float*)d_in[8];
  const float* wo = (const float*)d_in[9];
  const float* bo = (const float*)d_in[10];

  const long N = 8388608;             // B*H*S*D elements
  u16* qws  = (u16*)d_ws;             // bf16 intermediates
  u16* kws  = qws  + N;
  u16* vws  = kws  + N;               // attn output scratch
  u16* vtws = vws  + N;               // V, produced transposed by k_proj
  u16* wob  = vtws + N;               // 1M elems (wo bf16, linear)
  u16* wqb  = wob + 1048576;          // 4K elems each, FRAGMENT layout
  u16* wkb  = wqb + 4096;
  u16* wvb  = wkb + 4096;
  u16* aws  = vws;

  k_wconv <<<518,           256, 0, stream>>>(wo, wq, wk, wv, wob);
  k_proj  <<<dim3(128, 16), 256, 0, stream>>>(values, keys, query, wqb, wkb, wvb,
                                              bq, bk, bv, qws, kws, vtws);
  k_attn  <<<512,           512, 0, stream>>>(qws, kws, vtws, aws);
  k_oproj <<<512,           256, 0, stream>>>(aws, wob, bo, (float*)d_out);
}